// Round 4
// baseline (728.589 us; speedup 1.0000x reference)
//
#include <hip/hip_runtime.h>
#include <math.h>

// Problem: B=2, S=2048, d=1024, h=8, hd=128, hv=256, vd=2048, f=4096
#define RTOT 4096
#define SEQQ 2048

typedef unsigned int uint32;
typedef __attribute__((ext_vector_type(4))) float f32x4;
typedef __attribute__((ext_vector_type(16))) float f32x16;
typedef __attribute__((ext_vector_type(8))) short bf16x8;

__device__ __forceinline__ unsigned short f2bf(float f) {
  unsigned int u = __float_as_uint(f);
  u = (u + 0x7FFFu + ((u >> 16) & 1u)) >> 16;
  return (unsigned short)u;
}
__device__ __forceinline__ float bf2f(unsigned short h) {
  return __uint_as_float(((unsigned int)h) << 16);
}
__device__ __forceinline__ void gld16(const void* g, void* l) {
  __builtin_amdgcn_global_load_lds(
      (const __attribute__((address_space(1))) uint32*)g,
      (__attribute__((address_space(3))) uint32*)l, 16, 0, 0);
}

// ---------------- tiled transpose f32[R][C] -> bf16[C][R], batched z ----------
__global__ __launch_bounds__(256) void transpose_bf16(
    const float* __restrict__ in, unsigned short* __restrict__ out, int R, int C) {
  __shared__ float t[32][33];
  int z = blockIdx.z;
  in  += (size_t)z * R * C;
  out += (size_t)z * C * R;
  int r0 = blockIdx.x * 32, c0 = blockIdx.y * 32;
  int tx = threadIdx.x & 31, ty = threadIdx.x >> 5;
  #pragma unroll
  for (int i = 0; i < 4; ++i) {
    int r = ty + i * 8;
    t[r][tx] = in[(size_t)(r0 + r) * C + c0 + tx];
  }
  __syncthreads();
  #pragma unroll
  for (int i = 0; i < 4; ++i) {
    int c = ty + i * 8;
    out[(size_t)(c0 + c) * R + r0 + tx] = f2bf(t[tx][c]);
  }
}

// ---------------- f32 -> bf16 convert ----------------
__global__ __launch_bounds__(256) void cvt_bf16(
    const float* __restrict__ in, unsigned short* __restrict__ out, int n8) {
  int i = blockIdx.x * 256 + threadIdx.x;
  if (i >= n8) return;
  const float4* p = (const float4*)(in + (size_t)i * 8);
  float4 a = p[0], b = p[1];
  bf16x8 v;
  v[0] = (short)f2bf(a.x); v[1] = (short)f2bf(a.y); v[2] = (short)f2bf(a.z); v[3] = (short)f2bf(a.w);
  v[4] = (short)f2bf(b.x); v[5] = (short)f2bf(b.y); v[6] = (short)f2bf(b.z); v[7] = (short)f2bf(b.w);
  *(bf16x8*)(out + (size_t)i * 8) = v;
}

// ---------------- xpos coefficient tables [4][2048*64] f32 -------------------
__global__ __launch_bounds__(256) void tabgen(float* __restrict__ tab) {
  int i = blockIdx.x * 256 + threadIdx.x;   // 131072
  int pos = i >> 6, j = i & 63;
  float bs = (2.f * (float)j + 51.2f) * (1.f / 179.2f);
  float e = (float)pos * (1.f / 512.f);
  float sc = exp2f(e * log2f(bs));
  float invf = exp2f(-(float)j * (13.287712379549449f / 64.f));
  float su, cu;
  sincosf((float)pos * invf, &su, &cu);
  tab[i]            = cu * sc;   // cosQ
  tab[131072 + i]   = su * sc;   // sinQ
  float si = 1.f / sc;
  tab[262144 + i]   = cu * si;   // cosK
  tab[393216 + i]   = su * si;   // sinK
}

// ---------------- LayerNorm -> bf16 ----------------
__global__ __launch_bounds__(256) void ln_bf16(const float* __restrict__ x,
    const float* __restrict__ w, const float* __restrict__ b,
    unsigned short* __restrict__ out) {
  int row = blockIdx.x, tid = threadIdx.x;
  const float* xr = x + (size_t)row * 1024;
  float4 v = *(const float4*)(xr + tid * 4);
  float s  = v.x + v.y + v.z + v.w;
  float ss = v.x*v.x + v.y*v.y + v.z*v.z + v.w*v.w;
  #pragma unroll
  for (int o = 32; o > 0; o >>= 1) { s += __shfl_down(s, o); ss += __shfl_down(ss, o); }
  __shared__ float red[2][4];
  int wid = tid >> 6;
  if ((tid & 63) == 0) { red[0][wid] = s; red[1][wid] = ss; }
  __syncthreads();
  float st  = red[0][0] + red[0][1] + red[0][2] + red[0][3];
  float sst = red[1][0] + red[1][1] + red[1][2] + red[1][3];
  float mu   = st * (1.f / 1024.f);
  float var  = sst * (1.f / 1024.f) - mu * mu;
  float rstd = rsqrtf(var + 1e-5f);
  float4 wv = *(const float4*)(w + tid * 4);
  float4 bv = *(const float4*)(b + tid * 4);
  unsigned short o0 = f2bf((v.x - mu) * rstd * wv.x + bv.x);
  unsigned short o1 = f2bf((v.y - mu) * rstd * wv.y + bv.y);
  unsigned short o2 = f2bf((v.z - mu) * rstd * wv.z + bv.z);
  unsigned short o3 = f2bf((v.w - mu) * rstd * wv.w + bv.w);
  ushort4 o4 = make_ushort4(o0, o1, o2, o3);
  *(ushort4*)(out + (size_t)row * 1024 + tid * 4) = o4;
}

// ---------------- epilogues ----------------
enum { EPI_F32_RES = 0, EPI_BF16 = 1, EPI_XPOS = 2, EPI_GELU = 4, EPI_BRES = 5,
       EPI_QKG = 6, EPI_QG = 7 };

struct EpiP {
  void* C; int ldc;
  const float* bias; const float* resid;
  const float* tab;                       // xpos tables base (kernel-specific offset)
  unsigned short* oQ; unsigned short* oK; unsigned short* oG;
};

__device__ __forceinline__ float xpos_rot(float v, int m, int n,
                                          const float* tc, const float* ts) {
  float p = __shfl_xor(v, 1);
  int j = (n & 127) >> 1;
  int pos = m & (SEQQ - 1);
  float c = tc[pos * 64 + j], s = ts[pos * 64 + j];
  return (n & 1) ? (v * c + p * s) : (v * c - p * s);
}

template<int EPI>
__device__ __forceinline__ void epi_store(size_t m, int n, int N0, float v, const EpiP& P) {
  if constexpr (EPI == EPI_BF16) {
    ((unsigned short*)P.C)[m * P.ldc + n] = f2bf(v);
  } else if constexpr (EPI == EPI_XPOS) {
    v = xpos_rot(v, (int)m, n, P.tab, P.tab + 131072);
    ((unsigned short*)P.C)[m * P.ldc + n] = f2bf(v);
  } else if constexpr (EPI == EPI_GELU) {
    v += P.bias[n];
    v = 0.5f * v * (1.f + erff(v * 0.70710678f));
    ((unsigned short*)P.C)[m * P.ldc + n] = f2bf(v);
  } else if constexpr (EPI == EPI_BRES) {
    v += P.bias[n] + P.resid[m * P.ldc + n];
    ((float*)P.C)[m * P.ldc + n] = v;
  } else if constexpr (EPI == EPI_QKG) {
    if (N0 < 1024) {
      v = xpos_rot(v, (int)m, n, P.tab, P.tab + 131072);
      P.oQ[m * 1024 + n] = f2bf(v);
    } else if (N0 < 2048) {
      int nl = n - 1024;
      v = xpos_rot(v, (int)m, nl, P.tab + 262144, P.tab + 393216);
      P.oK[m * 1024 + nl] = f2bf(v);
    } else {
      int nl = n - 2048;
      P.oG[m * 2048 + nl] = f2bf(v / (1.f + expf(-v)));
    }
  } else if constexpr (EPI == EPI_QG) {
    if (N0 < 1024) {
      v = xpos_rot(v, (int)m, n, P.tab, P.tab + 131072);
      P.oQ[m * 1024 + n] = f2bf(v);
    } else {
      int nl = n - 1024;
      P.oG[m * 2048 + nl] = f2bf(v / (1.f + expf(-v)));
    }
  } else {  // EPI_F32_RES
    v += P.resid[m * P.ldc + n];
    ((float*)P.C)[m * P.ldc + n] = v;
  }
}

// ---------------- MFMA GEMM 128x128: C = A[M][K] * Bt[N][K]^T ----------------
template<int EPI>
__global__ __launch_bounds__(256) void gemm_mfma(
    const unsigned short* __restrict__ A, int lda,
    const unsigned short* __restrict__ Bt, int ldb, int K, EpiP P) {
  __shared__ __align__(16) unsigned short As[128 * 32];
  __shared__ __align__(16) unsigned short Bs[128 * 32];
  const int tid = threadIdx.x, w = tid >> 6, lane = tid & 63;
  const int M0 = blockIdx.y * 128, N0 = blockIdx.x * 128;
  const int fr = lane & 15, fs = lane >> 4;
  const int srow = lane >> 2, sp = lane & 3;

  f32x4 zf = {0.f, 0.f, 0.f, 0.f};
  f32x4 acc[4][4];
  #pragma unroll
  for (int i = 0; i < 4; ++i)
    #pragma unroll
    for (int j = 0; j < 4; ++j) acc[i][j] = zf;

  for (int k0 = 0; k0 < K; k0 += 32) {
    __syncthreads();
    #pragma unroll
    for (int c = 0; c < 4; ++c) {
      int ch = w * 4 + c;
      int cc = ch & 7;
      int row = cc * 16 + srow;
      int so = sp ^ ((row >> 1) & 3);
      if (ch < 8) gld16(A  + (size_t)(M0 + row) * lda + k0 + so * 8, As + cc * 512);
      else        gld16(Bt + (size_t)(N0 + row) * ldb + k0 + so * 8, Bs + cc * 512);
    }
    __syncthreads();
    bf16x8 af[4], bfr[4];
    #pragma unroll
    for (int mi = 0; mi < 4; ++mi) {
      int row = (w >> 1) * 64 + mi * 16 + fr;
      af[mi] = *(const bf16x8*)(As + row * 32 + (fs ^ ((row >> 1) & 3)) * 8);
    }
    #pragma unroll
    for (int ni = 0; ni < 4; ++ni) {
      int row = (w & 1) * 64 + ni * 16 + fr;
      bfr[ni] = *(const bf16x8*)(Bs + row * 32 + (fs ^ ((row >> 1) & 3)) * 8);
    }
    #pragma unroll
    for (int mi = 0; mi < 4; ++mi)
      #pragma unroll
      for (int ni = 0; ni < 4; ++ni)
        acc[mi][ni] = __builtin_amdgcn_mfma_f32_16x16x32_bf16(af[mi], bfr[ni], acc[mi][ni], 0, 0, 0);
  }

  #pragma unroll
  for (int mi = 0; mi < 4; ++mi)
    #pragma unroll
    for (int r = 0; r < 4; ++r) {
      size_t m = M0 + (w >> 1) * 64 + mi * 16 + fs * 4 + r;
      #pragma unroll
      for (int ni = 0; ni < 4; ++ni) {
        int n = N0 + (w & 1) * 64 + ni * 16 + fr;
        epi_store<EPI>(m, n, N0, acc[mi][ni][r], P);
      }
    }
}

// ---------------- MFMA GEMM 128x64 (for N=1024 shapes): better occupancy ----
template<int EPI>
__global__ __launch_bounds__(256) void gemm_bn64(
    const unsigned short* __restrict__ A, int lda,
    const unsigned short* __restrict__ Bt, int ldb, int K, EpiP P) {
  __shared__ __align__(16) unsigned short As[128 * 32];
  __shared__ __align__(16) unsigned short Bs[64 * 32];
  const int tid = threadIdx.x, w = tid >> 6, lane = tid & 63;
  const int M0 = blockIdx.y * 128, N0 = blockIdx.x * 64;
  const int fr = lane & 15, fs = lane >> 4;
  const int srow = lane >> 2, sp = lane & 3;

  f32x4 zf = {0.f, 0.f, 0.f, 0.f};
  f32x4 acc[2][4];
  #pragma unroll
  for (int i = 0; i < 2; ++i)
    #pragma unroll
    for (int j = 0; j < 4; ++j) acc[i][j] = zf;

  for (int k0 = 0; k0 < K; k0 += 32) {
    __syncthreads();
    #pragma unroll
    for (int c = 0; c < 3; ++c) {
      int ch = w * 3 + c;                  // 12 chunks: 8 A + 4 B
      if (ch < 8) {
        int row = ch * 16 + srow;
        int so = sp ^ ((row >> 1) & 3);
        gld16(A + (size_t)(M0 + row) * lda + k0 + so * 8, As + ch * 512);
      } else {
        int bch = ch - 8;
        int row = bch * 16 + srow;
        int so = sp ^ ((row >> 1) & 3);
        gld16(Bt + (size_t)(N0 + row) * ldb + k0 + so * 8, Bs + bch * 512);
      }
    }
    __syncthreads();
    bf16x8 af[2], bfr[4];
    #pragma unroll
    for (int mi = 0; mi < 2; ++mi) {
      int row = w * 32 + mi * 16 + fr;
      af[mi] = *(const bf16x8*)(As + row * 32 + (fs ^ ((row >> 1) & 3)) * 8);
    }
    #pragma unroll
    for (int ni = 0; ni < 4; ++ni) {
      int row = ni * 16 + fr;
      bfr[ni] = *(const bf16x8*)(Bs + row * 32 + (fs ^ ((row >> 1) & 3)) * 8);
    }
    #pragma unroll
    for (int mi = 0; mi < 2; ++mi)
      #pragma unroll
      for (int ni = 0; ni < 4; ++ni)
        acc[mi][ni] = __builtin_amdgcn_mfma_f32_16x16x32_bf16(af[mi], bfr[ni], acc[mi][ni], 0, 0, 0);
  }

  #pragma unroll
  for (int mi = 0; mi < 2; ++mi)
    #pragma unroll
    for (int r = 0; r < 4; ++r) {
      size_t m = M0 + w * 32 + mi * 16 + fs * 4 + r;
      #pragma unroll
      for (int ni = 0; ni < 4; ++ni) {
        int n = N0 + ni * 16 + fr;
        epi_store<EPI>(m, n, N0, acc[mi][ni][r], P);
      }
    }
}

// ---------------- MFMA retention, 32x32 swapped-QK, in-register P -----------
// 512 blocks, 4 waves. Block = 64 q-rows; wave (m=w>>1, n=w&1): 32 q x 128 v.
// Double-buffered K/V staging; S^T = mfma(K,Q) so P is lane-local for PV.
__global__ __launch_bounds__(256) void retention_mfma(
    const unsigned short* __restrict__ Qx, const unsigned short* __restrict__ Kx,
    const unsigned short* __restrict__ VT, const unsigned short* __restrict__ Gate,
    const float* __restrict__ gnw, const float* __restrict__ gnb,
    unsigned short* __restrict__ Gout) {
  __shared__ __align__(16) unsigned short Ks[2][32 * 128];   // [t][e], 16B-slot swz by t&15
  __shared__ __align__(16) unsigned short Vs[2][256 * 32];   // [v][t], 16B-slot swz by (v>>1)&3
  __shared__ float redS[2][2][32], redQ[2][2][32];
  const int tid = threadIdx.x, w = tid >> 6, lane = tid & 63;
  int bid = blockIdx.x, qt, h, b;
  if (bid < 256) { qt = 31 - (bid >> 3); h = bid & 7; b = 0; }
  else           { int k = bid - 256; qt = k >> 3; h = k & 7; b = 1; }
  const int q0 = qt * 64;
  const int m = w >> 1, n = w & 1;
  const int q0m = q0 + m * 32;
  const int ql = lane & 31, hi = lane >> 5, hi4 = hi * 4;

  float gamma = 1.f - expf(-3.4657359028f - 0.3960841032f * (float)h);
  float l2g = log2f(gamma);           // negative
  float negl2g = -l2g;

  // Q fragments (B-operand): col q = ql, k = e = ks*16 + hi*8 + i
  size_t qrow = (size_t)b * SEQQ + q0m + ql;
  bf16x8 qf[8];
  #pragma unroll
  for (int ks = 0; ks < 8; ++ks)
    qf[ks] = *(const bf16x8*)(Qx + qrow * 1024 + h * 128 + ks * 16 + hi * 8);

  float fqlane = exp2f((float)(q0m + ql) * l2g);     // gamma^q (per-lane const)
  float ftoff[16];
  #pragma unroll
  for (int r = 0; r < 16; ++r) {
    int toff = (r & 3) + 8 * (r >> 2) + hi4;
    ftoff[r] = exp2f((float)toff * negl2g);          // gamma^-toff
  }

  f32x16 yacc[4];
  #pragma unroll
  for (int nv = 0; nv < 4; ++nv)
    #pragma unroll
    for (int i = 0; i < 16; ++i) yacc[nv][i] = 0.f;

  int cutoff = (int)(27.f / negl2g);
  int t_start = q0 - cutoff;
  if (t_start < 0) t_start = 0;
  t_start &= ~31;
  const size_t kbase = (size_t)b * SEQQ;

  auto STAGE = [&](int buf, int t0) {
    #pragma unroll
    for (int c = 0; c < 2; ++c) {          // K: 8 chunks of 4 rows x 256B
      int ch = w * 2 + c;
      int row = ch * 4 + (lane >> 4);
      int so = (lane & 15) ^ (row & 15);
      gld16(Kx + (kbase + t0 + row) * 1024 + h * 128 + so * 8, &Ks[buf][ch * 512]);
    }
    #pragma unroll
    for (int c = 0; c < 4; ++c) {          // V: 16 chunks of 16 rows x 64B
      int ch = w * 4 + c;
      int v = ch * 16 + (lane >> 2);
      int so = (lane & 3) ^ ((v >> 1) & 3);
      gld16(VT + (size_t)(h * 256 + v) * RTOT + kbase + t0 + so * 8, &Vs[buf][ch * 512]);
    }
  };

  STAGE(0, t_start);
  __syncthreads();
  int cur = 0;
  for (int t0 = t_start; t0 < q0 + 64; t0 += 32) {
    if (t0 + 32 < q0 + 64) STAGE(cur ^ 1, t0 + 32);   // prefetch next tile

    // S^T[t][q] = sum_e K[t][e] Q[q][e]   (A = K-frag row t=ql, B = Q col q=ql)
    f32x16 sacc;
    #pragma unroll
    for (int i = 0; i < 16; ++i) sacc[i] = 0.f;
    #pragma unroll
    for (int ks = 0; ks < 8; ++ks) {
      int sl = ((ks * 2 + hi) ^ (ql & 15)) * 8;
      bf16x8 kf = *(const bf16x8*)(&Ks[cur][ql * 128 + sl]);
      sacc = __builtin_amdgcn_mfma_f32_32x32x16_bf16(kf, qf[ks], sacc, 0, 0, 0);
    }

    // decay + causal mask + bf16-pack (P stays in registers)
    float fsc = fqlane * exp2f((float)t0 * negl2g);   // gamma^(q - t0)
    uint32 wd[8];
    #pragma unroll
    for (int r2 = 0; r2 < 8; ++r2) {
      int ra = r2 * 2, rb = ra + 1;
      float va = sacc[ra] * (fsc * ftoff[ra]);
      float vb = sacc[rb] * (fsc * ftoff[rb]);
      int ta = t0 + (ra & 3) + 8 * (ra >> 2) + hi4;
      va = (q0m + ql >= ta)     ? va : 0.f;
      vb = (q0m + ql >= ta + 1) ? vb : 0.f;
      wd[r2] = (uint32)f2bf(va) | ((uint32)f2bf(vb) << 16);
    }
    uint32 xd[8];
    #pragma unroll
    for (int i = 0; i < 8; ++i) xd[i] = (uint32)__shfl_xor((int)wd[i], 32);

    // PV: Y[q][v] += P[q][t] V[t][v]
    #pragma unroll
    for (int kh = 0; kh < 2; ++kh) {
      int o = kh * 4;
      union { uint32 u[4]; bf16x8 v8; } pa;
      if (hi == 0) { pa.u[0] = wd[o+0]; pa.u[1] = wd[o+1]; pa.u[2] = xd[o+0]; pa.u[3] = xd[o+1]; }
      else         { pa.u[0] = xd[o+2]; pa.u[1] = xd[o+3]; pa.u[2] = wd[o+2]; pa.u[3] = wd[o+3]; }
      #pragma unroll
      for (int nv = 0; nv < 4; ++nv) {
        int v = n * 128 + nv * 32 + ql;
        int sl = ((kh * 2 + hi) ^ ((v >> 1) & 3)) * 8;
        bf16x8 vf = *(const bf16x8*)(&Vs[cur][v * 32 + sl]);
        yacc[nv] = __builtin_amdgcn_mfma_f32_32x32x16_bf16(pa.v8, vf, yacc[nv], 0, 0, 0);
      }
    }
    __syncthreads();
    cur ^= 1;
  }

  // ---- epilogue: groupnorm over 256 v (cross-wave n=0/1) * affine * silu gate
  float ps[16], pq[16];
  #pragma unroll
  for (int r = 0; r < 16; ++r) {
    float s = yacc[0][r] + yacc[1][r] + yacc[2][r] + yacc[3][r];
    float q2 = yacc[0][r]*yacc[0][r] + yacc[1][r]*yacc[1][r]
             + yacc[2][r]*yacc[2][r] + yacc[3][r]*yacc[3][r];
    #pragma unroll
    for (int msk = 1; msk < 32; msk <<= 1) {
      s  += __shfl_xor(s, msk);
      q2 += __shfl_xor(q2, msk);
    }
    ps[r] = s; pq[r] = q2;
  }
  if (ql == 0) {
    #pragma unroll
    for (int r = 0; r < 16; ++r) {
      int qof = (r & 3) + 8 * (r >> 2) + hi4;
      redS[m][n][qof] = ps[r];
      redQ[m][n][qof] = pq[r];
    }
  }
  __syncthreads();
  float gwv[4], gbv[4];
  #pragma unroll
  for (int nv = 0; nv < 4; ++nv) {
    int v = n * 128 + nv * 32 + ql;
    gwv[nv] = gnw[h * 256 + v];
    gbv[nv] = gnb[h * 256 + v];
  }
  #pragma unroll
  for (int r = 0; r < 16; ++r) {
    int qof = (r & 3) + 8 * (r >> 2) + hi4;
    float S  = redS[m][0][qof] + redS[m][1][qof];
    float SQ = redQ[m][0][qof] + redQ[m][1][qof];
    float mu = S * (1.f / 256.f);
    float var = SQ * (1.f / 256.f) - mu * mu;
    float rstd = rsqrtf(var + 1e-5f);
    size_t mrow = (size_t)b * SEQQ + q0m + qof;
    const unsigned short* grow = Gate + mrow * 2048 + h * 256;
    unsigned short* orow = Gout + mrow * 2048 + h * 256;
    #pragma unroll
    for (int nv = 0; nv < 4; ++nv) {
      int v = n * 128 + nv * 32 + ql;
      float g = bf2f(grow[v]);
      float yn = (yacc[nv][r] - mu) * rstd * gwv[nv] + gbv[nv];
      orow[v] = f2bf((g / (1.f + expf(-g))) * yn);
    }
  }
}

// =============================== host ========================================
extern "C" void kernel_launch(void* const* d_in, const int* in_sizes, int n_in,
                              void* d_out, int out_size, void* d_ws, size_t ws_size,
                              hipStream_t stream) {
  const float* X    = (const float*)d_in[0];
  const float* mem  = (const float*)d_in[1];
  const float* ln1w = (const float*)d_in[2];
  const float* ln1b = (const float*)d_in[3];
  const float* ln2w = (const float*)d_in[4];
  const float* ln2b = (const float*)d_in[5];
  const float* Wq   = (const float*)d_in[6];
  const float* Wk   = (const float*)d_in[7];
  const float* Wv   = (const float*)d_in[8];
  const float* Wg   = (const float*)d_in[9];
  const float* Wo   = (const float*)d_in[10];
  const float* gnw  = (const float*)d_in[11];
  const float* gnb  = (const float*)d_in[12];
  const float* cWq  = (const float*)d_in[13];
  const float* cWk  = (const float*)d_in[14];
  const float* cWv  = (const float*)d_in[15];
  const float* cWg  = (const float*)d_in[16];
  const float* cWo  = (const float*)d_in[17];
  const float* cgnw = (const float*)d_in[18];
  const float* cgnb = (const float*)d_in[19];
  const float* W1   = (const float*)d_in[20];
  const float* b1   = (const float*)d_in[21];
  const float* W2   = (const float*)d_in[22];
  const float* b2   = (const float*)d_in[23];
  float* out = (float*)d_out;

  const size_t MB = 1024ull * 1024ull;
  if (ws_size < 106 * MB) return;
  unsigned char* W8 = (unsigned char*)d_ws;
  unsigned short* WqkgT = (unsigned short*)(W8 + 0 * MB);   // 8MB [4096][1024]
  unsigned short* WvT   = (unsigned short*)(W8 + 8 * MB);   // 4MB [2048][1024]
  unsigned short* WoT   = (unsigned short*)(W8 + 12 * MB);  // 4MB [1024][2048]
  unsigned short* cQGT  = (unsigned short*)(W8 + 16 * MB);  // 6MB [3072][1024]
  unsigned short* cWkT  = (unsigned short*)(W8 + 22 * MB);  // 2MB
  unsigned short* cWvT  = (unsigned short*)(W8 + 24 * MB);  // 4MB
  unsigned short* cWoT  = (unsigned short*)(W8 + 28 * MB);  // 4MB
  float*          tab   = (float*)(W8 + 32 * MB);           // 2MB
  unsigned short* hbuf  = (unsigned short*)(W8 + 34 * MB);  // 8MB
  unsigned short* Qx    = (unsigned short*)(W8 + 42 * MB);  // 8MB (later W1T)
  unsigned short* Kx    = (unsigned short*)(W8 + 50 * MB);  // 8MB (later W2T)
  unsigned short* W1T   = Qx;
  unsigned short* W2T   = Kx;
  unsigned short* VTb   = (unsigned short*)(W8 + 58 * MB);  // 16MB
  unsigned short* Gg    = (unsigned short*)(W8 + 74 * MB);  // 16MB
  unsigned short* Tb    = VTb;                               // FFN mid 32MB
  unsigned short* GoutB = (unsigned short*)(W8 + 90 * MB);  // 16MB
  unsigned short* mem16 = GoutB;                             // 8MB overlay

  // ---- weight prep ----
  transpose_bf16<<<dim3(32, 4, 8),  256, 0, stream>>>(Wq,  WqkgT,               1024, 128);
  transpose_bf16<<<dim3(32, 4, 8),  256, 0, stream>>>(Wk,  WqkgT + 1024 * 1024, 1024, 128);
  transpose_bf16<<<dim3(32, 64, 1), 256, 0, stream>>>(Wg,  WqkgT + 2048 * 1024, 1024, 2048);
  transpose_bf16<<<dim3(32, 8, 8),  256, 0, stream>>>(Wv,  WvT,  1024, 256);
  transpose_bf16<<<dim3(64, 32, 1), 256, 0, stream>>>(Wo,  WoT,  2048, 1024);
  transpose_bf16<<<dim3(32, 4, 8),  256, 0, stream>>>(cWq, cQGT,               1024, 128);
  transpose_bf16<<<dim3(32, 64, 1), 256, 0, stream>>>(cWg, cQGT + 1024 * 1024, 1024, 2048);
  transpose_bf16<<<dim3(32, 4, 8),  256, 0, stream>>>(cWk, cWkT, 1024, 128);
  transpose_bf16<<<dim3(32, 8, 8),  256, 0, stream>>>(cWv, cWvT, 1024, 256);
  transpose_bf16<<<dim3(64, 32, 1), 256, 0, stream>>>(cWo, cWoT, 2048, 1024);
  tabgen<<<512, 256, 0, stream>>>(tab);

  EpiP P{};

  // ---- block 1: self retention ----
  ln_bf16<<<RTOT, 256, 0, stream>>>(X, ln1w, ln1b, hbuf);
  P = EpiP{nullptr, 0, nullptr, nullptr, tab, Qx, Kx, Gg};
  gemm_mfma<EPI_QKG><<<dim3(32, 32), 256, 0, stream>>>(hbuf, 1024, WqkgT, 1024, 1024, P);
  P = EpiP{VTb, 4096, nullptr, nullptr, nullptr, nullptr, nullptr, nullptr};
  gemm_mfma<EPI_BF16><<<dim3(32, 16), 256, 0, stream>>>(WvT, 1024, hbuf, 1024, 1024, P);
  retention_mfma<<<dim3(512), 256, 0, stream>>>(Qx, Kx, VTb, Gg, gnw, gnb, GoutB);
  P = EpiP{out, 1024, nullptr, X, nullptr, nullptr, nullptr, nullptr};
  gemm_bn64<EPI_F32_RES><<<dim3(16, 32), 256, 0, stream>>>(GoutB, 2048, WoT, 2048, 2048, P);

  // ---- block 2: cross retention ----
  cvt_bf16<<<2048, 256, 0, stream>>>(mem, mem16, 524288);
  ln_bf16<<<RTOT, 256, 0, stream>>>(out, ln2w, ln2b, hbuf);
  P = EpiP{nullptr, 0, nullptr, nullptr, tab, Qx, nullptr, Gg};
  gemm_mfma<EPI_QG><<<dim3(24, 32), 256, 0, stream>>>(hbuf, 1024, cQGT, 1024, 1024, P);
  P = EpiP{Kx, 1024, nullptr, nullptr, tab + 262144, nullptr, nullptr, nullptr};
  gemm_bn64<EPI_XPOS><<<dim3(16, 32), 256, 0, stream>>>(mem16, 1024, cWkT, 1024, 1024, P);
  P = EpiP{VTb, 4096, nullptr, nullptr, nullptr, nullptr, nullptr, nullptr};
  gemm_mfma<EPI_BF16><<<dim3(32, 16), 256, 0, stream>>>(cWvT, 1024, mem16, 1024, 1024, P);
  retention_mfma<<<dim3(512), 256, 0, stream>>>(Qx, Kx, VTb, Gg, cgnw, cgnb, GoutB);
  P = EpiP{out, 1024, nullptr, out, nullptr, nullptr, nullptr, nullptr};
  gemm_bn64<EPI_F32_RES><<<dim3(16, 32), 256, 0, stream>>>(GoutB, 2048, cWoT, 2048, 2048, P);

  // ---- FFN ----
  transpose_bf16<<<dim3(32, 128, 1), 256, 0, stream>>>(W1, W1T, 1024, 4096);
  transpose_bf16<<<dim3(128, 32, 1), 256, 0, stream>>>(W2, W2T, 4096, 1024);
  ln_bf16<<<RTOT, 256, 0, stream>>>(out, ln2w, ln2b, hbuf);
  P = EpiP{Tb, 4096, b1, nullptr, nullptr, nullptr, nullptr, nullptr};
  gemm_mfma<EPI_GELU><<<dim3(32, 32), 256, 0, stream>>>(hbuf, 1024, W1T, 1024, 1024, P);
  P = EpiP{out, 1024, b2, out, nullptr, nullptr, nullptr, nullptr};
  gemm_bn64<EPI_BRES><<<dim3(16, 32), 256, 0, stream>>>(Tb, 4096, W2T, 4096, 4096, P);
}

// Round 5
// 667.124 us; speedup vs baseline: 1.0921x; 1.0921x over previous
//
#include <hip/hip_runtime.h>
#include <math.h>

// Problem: B=2, S=2048, d=1024, h=8, hd=128, hv=256, vd=2048, f=4096
#define RTOT 4096
#define SEQQ 2048

typedef unsigned int uint32;
typedef __attribute__((ext_vector_type(4))) float f32x4;
typedef __attribute__((ext_vector_type(8))) short bf16x8;

__device__ __forceinline__ unsigned short f2bf(float f) {
  unsigned int u = __float_as_uint(f);
  u = (u + 0x7FFFu + ((u >> 16) & 1u)) >> 16;
  return (unsigned short)u;
}
__device__ __forceinline__ float bf2f(unsigned short h) {
  return __uint_as_float(((unsigned int)h) << 16);
}
__device__ __forceinline__ void gld16(const void* g, void* l) {
  __builtin_amdgcn_global_load_lds(
      (const __attribute__((address_space(1))) uint32*)g,
      (__attribute__((address_space(3))) uint32*)l, 16, 0, 0);
}
__device__ __forceinline__ void bar() {
  asm volatile("" ::: "memory");
  __builtin_amdgcn_s_barrier();
  asm volatile("" ::: "memory");
}

// ---- tiled transpose f32[R][C] -> bf16[C][R], batched z; optional xpos perm --
// perm (C==128 heads): orig col c -> row 64*(c>>6) + ((c&1)<<5) + ((c&63)>>1)
__global__ __launch_bounds__(256) void transpose_bf16(
    const float* __restrict__ in, unsigned short* __restrict__ out, int R, int C,
    int perm) {
  __shared__ float t[32][33];
  int z = blockIdx.z;
  in  += (size_t)z * R * C;
  out += (size_t)z * C * R;
  int r0 = blockIdx.x * 32, c0 = blockIdx.y * 32;
  int tx = threadIdx.x & 31, ty = threadIdx.x >> 5;
  #pragma unroll
  for (int i = 0; i < 4; ++i) {
    int r = ty + i * 8;
    t[r][tx] = in[(size_t)(r0 + r) * C + c0 + tx];
  }
  __syncthreads();
  #pragma unroll
  for (int i = 0; i < 4; ++i) {
    int cc = c0 + ty + i * 8;
    if (perm) cc = 64 * (cc >> 6) + ((cc & 1) << 5) + ((cc & 63) >> 1);
    out[(size_t)cc * R + r0 + tx] = f2bf(t[tx][ty + i * 8]);
  }
}

// ---------------- f32 -> bf16 convert ----------------
__global__ __launch_bounds__(256) void cvt_bf16(
    const float* __restrict__ in, unsigned short* __restrict__ out, int n8) {
  int i = blockIdx.x * 256 + threadIdx.x;
  if (i >= n8) return;
  const float4* p = (const float4*)(in + (size_t)i * 8);
  float4 a = p[0], b = p[1];
  bf16x8 v;
  v[0] = (short)f2bf(a.x); v[1] = (short)f2bf(a.y); v[2] = (short)f2bf(a.z); v[3] = (short)f2bf(a.w);
  v[4] = (short)f2bf(b.x); v[5] = (short)f2bf(b.y); v[6] = (short)f2bf(b.z); v[7] = (short)f2bf(b.w);
  *(bf16x8*)(out + (size_t)i * 8) = v;
}

// ---------------- xpos coefficient tables [4][2048*64] f32 -------------------
__global__ __launch_bounds__(256) void tabgen(float* __restrict__ tab) {
  int i = blockIdx.x * 256 + threadIdx.x;   // 131072
  int pos = i >> 6, j = i & 63;
  float bs = (2.f * (float)j + 51.2f) * (1.f / 179.2f);
  float e = (float)pos * (1.f / 512.f);
  float sc = exp2f(e * log2f(bs));
  float invf = exp2f(-(float)j * (13.287712379549449f / 64.f));
  float su, cu;
  sincosf((float)pos * invf, &su, &cu);
  tab[i]            = cu * sc;   // cosQ
  tab[131072 + i]   = su * sc;   // sinQ
  float si = 1.f / sc;
  tab[262144 + i]   = cu * si;   // cosK
  tab[393216 + i]   = su * si;   // sinK
}

// ---------------- LayerNorm -> bf16 ----------------
__global__ __launch_bounds__(256) void ln_bf16(const float* __restrict__ x,
    const float* __restrict__ w, const float* __restrict__ b,
    unsigned short* __restrict__ out) {
  int row = blockIdx.x, tid = threadIdx.x;
  const float* xr = x + (size_t)row * 1024;
  float4 v = *(const float4*)(xr + tid * 4);
  float s  = v.x + v.y + v.z + v.w;
  float ss = v.x*v.x + v.y*v.y + v.z*v.z + v.w*v.w;
  #pragma unroll
  for (int o = 32; o > 0; o >>= 1) { s += __shfl_down(s, o); ss += __shfl_down(ss, o); }
  __shared__ float red[2][4];
  int wid = tid >> 6;
  if ((tid & 63) == 0) { red[0][wid] = s; red[1][wid] = ss; }
  __syncthreads();
  float st  = red[0][0] + red[0][1] + red[0][2] + red[0][3];
  float sst = red[1][0] + red[1][1] + red[1][2] + red[1][3];
  float mu   = st * (1.f / 1024.f);
  float var  = sst * (1.f / 1024.f) - mu * mu;
  float rstd = rsqrtf(var + 1e-5f);
  float4 wv = *(const float4*)(w + tid * 4);
  float4 bv = *(const float4*)(b + tid * 4);
  unsigned short o0 = f2bf((v.x - mu) * rstd * wv.x + bv.x);
  unsigned short o1 = f2bf((v.y - mu) * rstd * wv.y + bv.y);
  unsigned short o2 = f2bf((v.z - mu) * rstd * wv.z + bv.z);
  unsigned short o3 = f2bf((v.w - mu) * rstd * wv.w + bv.w);
  ushort4 o4 = make_ushort4(o0, o1, o2, o3);
  *(ushort4*)(out + (size_t)row * 1024 + tid * 4) = o4;
}

// ---------------- epilogues ----------------
enum { EPI_F32_RES = 0, EPI_BF16 = 1, EPI_XPOS = 2, EPI_GELU = 4, EPI_BRES = 5,
       EPI_QKG = 6, EPI_QG = 7 };

struct EpiP {
  void* C; int ldc;
  const float* bias; const float* resid;
  const float* tab;
  unsigned short* oQ; unsigned short* oK; unsigned short* oG;
};

template<int EPI>
__device__ __forceinline__ void epi_store(size_t m, int n, int N0, float v, const EpiP& P) {
  if constexpr (EPI == EPI_BF16) {
    ((unsigned short*)P.C)[m * P.ldc + n] = f2bf(v);
  } else if constexpr (EPI == EPI_GELU) {
    v += P.bias[n];
    v = 0.5f * v * (1.f + erff(v * 0.70710678f));
    ((unsigned short*)P.C)[m * P.ldc + n] = f2bf(v);
  } else if constexpr (EPI == EPI_BRES) {
    v += P.bias[n] + P.resid[m * P.ldc + n];
    ((float*)P.C)[m * P.ldc + n] = v;
  } else {  // EPI_F32_RES
    v += P.resid[m * P.ldc + n];
    ((float*)P.C)[m * P.ldc + n] = v;
  }
}

// ---------------- MFMA GEMM 128x128 (2-phase): C = A * Bt^T -----------------
template<int EPI>
__global__ __launch_bounds__(256) void gemm_mfma(
    const unsigned short* __restrict__ A, int lda,
    const unsigned short* __restrict__ Bt, int ldb, int K, EpiP P) {
  __shared__ __align__(16) unsigned short As[128 * 32];
  __shared__ __align__(16) unsigned short Bs[128 * 32];
  const int tid = threadIdx.x, w = tid >> 6, lane = tid & 63;
  const int M0 = blockIdx.y * 128, N0 = blockIdx.x * 128;
  const int fr = lane & 15, fs = lane >> 4;
  const int srow = lane >> 2, sp = lane & 3;

  f32x4 zf = {0.f, 0.f, 0.f, 0.f};
  f32x4 acc[4][4];
  #pragma unroll
  for (int i = 0; i < 4; ++i)
    #pragma unroll
    for (int j = 0; j < 4; ++j) acc[i][j] = zf;

  for (int k0 = 0; k0 < K; k0 += 32) {
    __syncthreads();
    #pragma unroll
    for (int c = 0; c < 4; ++c) {
      int ch = w * 4 + c;
      int cc = ch & 7;
      int row = cc * 16 + srow;
      int so = sp ^ ((row >> 1) & 3);
      if (ch < 8) gld16(A  + (size_t)(M0 + row) * lda + k0 + so * 8, As + cc * 512);
      else        gld16(Bt + (size_t)(N0 + row) * ldb + k0 + so * 8, Bs + cc * 512);
    }
    __syncthreads();
    bf16x8 af[4], bfr[4];
    #pragma unroll
    for (int mi = 0; mi < 4; ++mi) {
      int row = (w >> 1) * 64 + mi * 16 + fr;
      af[mi] = *(const bf16x8*)(As + row * 32 + (fs ^ ((row >> 1) & 3)) * 8);
    }
    #pragma unroll
    for (int ni = 0; ni < 4; ++ni) {
      int row = (w & 1) * 64 + ni * 16 + fr;
      bfr[ni] = *(const bf16x8*)(Bs + row * 32 + (fs ^ ((row >> 1) & 3)) * 8);
    }
    #pragma unroll
    for (int mi = 0; mi < 4; ++mi)
      #pragma unroll
      for (int ni = 0; ni < 4; ++ni)
        acc[mi][ni] = __builtin_amdgcn_mfma_f32_16x16x32_bf16(af[mi], bfr[ni], acc[mi][ni], 0, 0, 0);
  }

  #pragma unroll
  for (int mi = 0; mi < 4; ++mi)
    #pragma unroll
    for (int r = 0; r < 4; ++r) {
      size_t m = M0 + (w >> 1) * 64 + mi * 16 + fs * 4 + r;
      #pragma unroll
      for (int ni = 0; ni < 4; ++ni) {
        int n = N0 + (w & 1) * 64 + ni * 16 + fr;
        epi_store<EPI>(m, n, N0, acc[mi][ni][r], P);
      }
    }
}

// ---------------- MFMA GEMM 128x64 (N=1024 shapes) ----------------
template<int EPI>
__global__ __launch_bounds__(256) void gemm_bn64(
    const unsigned short* __restrict__ A, int lda,
    const unsigned short* __restrict__ Bt, int ldb, int K, EpiP P) {
  __shared__ __align__(16) unsigned short As[128 * 32];
  __shared__ __align__(16) unsigned short Bs[64 * 32];
  const int tid = threadIdx.x, w = tid >> 6, lane = tid & 63;
  const int M0 = blockIdx.y * 128, N0 = blockIdx.x * 64;
  const int fr = lane & 15, fs = lane >> 4;
  const int srow = lane >> 2, sp = lane & 3;

  f32x4 zf = {0.f, 0.f, 0.f, 0.f};
  f32x4 acc[2][4];
  #pragma unroll
  for (int i = 0; i < 2; ++i)
    #pragma unroll
    for (int j = 0; j < 4; ++j) acc[i][j] = zf;

  for (int k0 = 0; k0 < K; k0 += 32) {
    __syncthreads();
    #pragma unroll
    for (int c = 0; c < 3; ++c) {
      int ch = w * 3 + c;
      if (ch < 8) {
        int row = ch * 16 + srow;
        int so = sp ^ ((row >> 1) & 3);
        gld16(A + (size_t)(M0 + row) * lda + k0 + so * 8, As + ch * 512);
      } else {
        int bch = ch - 8;
        int row = bch * 16 + srow;
        int so = sp ^ ((row >> 1) & 3);
        gld16(Bt + (size_t)(N0 + row) * ldb + k0 + so * 8, Bs + bch * 512);
      }
    }
    __syncthreads();
    bf16x8 af[2], bfr[4];
    #pragma unroll
    for (int mi = 0; mi < 2; ++mi) {
      int row = w * 32 + mi * 16 + fr;
      af[mi] = *(const bf16x8*)(As + row * 32 + (fs ^ ((row >> 1) & 3)) * 8);
    }
    #pragma unroll
    for (int ni = 0; ni < 4; ++ni) {
      int row = ni * 16 + fr;
      bfr[ni] = *(const bf16x8*)(Bs + row * 32 + (fs ^ ((row >> 1) & 3)) * 8);
    }
    #pragma unroll
    for (int mi = 0; mi < 2; ++mi)
      #pragma unroll
      for (int ni = 0; ni < 4; ++ni)
        acc[mi][ni] = __builtin_amdgcn_mfma_f32_16x16x32_bf16(af[mi], bfr[ni], acc[mi][ni], 0, 0, 0);
  }

  if constexpr (EPI == EPI_XPOS) {
    // pair-in-lane xpos: cols permuted at transpose; pairs at (ni, ni+2)
    int gsel = (N0 >> 6) & 1;
    #pragma unroll
    for (int mi = 0; mi < 2; ++mi)
      #pragma unroll
      for (int r = 0; r < 4; ++r) {
        size_t m = M0 + w * 32 + mi * 16 + fs * 4 + r;
        int pos = (int)(m & (SEQQ - 1));
        #pragma unroll
        for (int ni = 0; ni < 2; ++ni) {
          int j = gsel * 32 + ni * 16 + fr;
          float cs = P.tab[pos * 64 + j], sn = P.tab[131072 + pos * 64 + j];
          float ve = acc[mi][ni][r], vo = acc[mi][ni + 2][r];
          unsigned short* dst = (unsigned short*)P.C;
          dst[m * P.ldc + N0 + ni * 16 + fr]       = f2bf(ve * cs - vo * sn);
          dst[m * P.ldc + N0 + (ni + 2) * 16 + fr] = f2bf(vo * cs + ve * sn);
        }
      }
  } else {
    #pragma unroll
    for (int mi = 0; mi < 2; ++mi)
      #pragma unroll
      for (int r = 0; r < 4; ++r) {
        size_t m = M0 + w * 32 + mi * 16 + fs * 4 + r;
        #pragma unroll
        for (int ni = 0; ni < 4; ++ni) {
          int n = N0 + ni * 16 + fr;
          epi_store<EPI>(m, n, N0, acc[mi][ni][r], P);
        }
      }
  }
}

// ---------------- 256x256 8-wave GEMM, 4-deep counted-vmcnt pipeline --------
// K=1024 fixed (NT=32, BK=32). 512 thr. Wave (wm=w>>2, wn=w&3): 128x64 out.
template<int EPI>
__global__ __launch_bounds__(512, 2) void gemm256(
    const unsigned short* __restrict__ A,
    const unsigned short* __restrict__ Bt,
    int nbx, EpiP P) {
  __shared__ __align__(16) unsigned short lds[4][2][8192];  // [buf][A|B][256*32]
  const int tid = threadIdx.x, w = tid >> 6, lane = tid & 63;
  // XCD-bijective swizzle (gridDim.x % 8 == 0)
  int cpx = (int)gridDim.x >> 3;
  int sbid = ((int)blockIdx.x & 7) * cpx + ((int)blockIdx.x >> 3);
  int by = sbid / nbx, bx = sbid - by * nbx;
  const int M0 = by * 256, N0 = bx * 256;
  const int wm = w >> 2, wn = w & 3;
  const int fr = lane & 15, fs = lane >> 4;
  const int srow = lane >> 2;
  const int sslot = (lane & 3) ^ ((lane >> 3) & 3);
  const int rsw = (fr >> 1) & 3;

  f32x4 acc[8][4];
  #pragma unroll
  for (int i = 0; i < 8; ++i)
    #pragma unroll
    for (int j = 0; j < 4; ++j) acc[i][j] = {0.f, 0.f, 0.f, 0.f};

  auto STAGE = [&](int t, int buf) {
    int k0 = t * 32;
    #pragma unroll
    for (int j = 0; j < 4; ++j) {
      int c = w * 4 + j;
      if (c < 16)
        gld16(A  + (size_t)(M0 + c * 16 + srow) * 1024 + k0 + sslot * 8,
              &lds[buf][0][c * 512]);
      else
        gld16(Bt + (size_t)(N0 + (c - 16) * 16 + srow) * 1024 + k0 + sslot * 8,
              &lds[buf][1][(c - 16) * 512]);
    }
  };
  auto COMPUTE = [&](int t) {
    const unsigned short* la = &lds[t & 3][0][wm * 128 * 32];
    const unsigned short* lb = &lds[t & 3][1][wn * 64 * 32];
    bf16x8 a[8], b[4];
    #pragma unroll
    for (int ni = 0; ni < 4; ++ni)
      b[ni] = *(const bf16x8*)(lb + (ni * 16 + fr) * 32 + ((fs ^ rsw) * 8));
    #pragma unroll
    for (int mi = 0; mi < 8; ++mi)
      a[mi] = *(const bf16x8*)(la + (mi * 16 + fr) * 32 + ((fs ^ rsw) * 8));
    #pragma unroll
    for (int mi = 0; mi < 8; ++mi)
      #pragma unroll
      for (int ni = 0; ni < 4; ++ni)
        acc[mi][ni] = __builtin_amdgcn_mfma_f32_16x16x32_bf16(a[mi], b[ni], acc[mi][ni], 0, 0, 0);
  };

  STAGE(0, 0); STAGE(1, 1); STAGE(2, 2);
  for (int t = 0; t < 29; ++t) {
    STAGE(t + 3, (t + 3) & 3);
    asm volatile("s_waitcnt vmcnt(12)" ::: "memory");
    bar();
    COMPUTE(t);
    bar();
  }
  asm volatile("s_waitcnt vmcnt(8)" ::: "memory");
  bar(); COMPUTE(29); bar();
  asm volatile("s_waitcnt vmcnt(4)" ::: "memory");
  bar(); COMPUTE(30); bar();
  asm volatile("s_waitcnt vmcnt(0)" ::: "memory");
  bar(); COMPUTE(31);

  // ----------------- epilogue -----------------
  if constexpr (EPI == EPI_GELU) {
    #pragma unroll
    for (int mi = 0; mi < 8; ++mi)
      #pragma unroll
      for (int r = 0; r < 4; ++r) {
        size_t m = M0 + wm * 128 + mi * 16 + fs * 4 + r;
        #pragma unroll
        for (int ni = 0; ni < 4; ++ni) {
          int n = N0 + wn * 64 + ni * 16 + fr;
          float v = acc[mi][ni][r] + P.bias[n];
          v = 0.5f * v * (1.f + erff(v * 0.70710678f));
          ((unsigned short*)P.C)[m * P.ldc + n] = f2bf(v);
        }
      }
  } else {  // EPI_QKG / EPI_QG
    const int nb = N0 + wn * 64;   // 64-aligned, wave-uniform
    const bool isQ = nb < 1024;
    const bool isK = (EPI == EPI_QKG) && !isQ && (nb < 2048);
    if (isQ || isK) {
      const float* tc = isK ? P.tab + 262144 : P.tab;
      const float* ts = tc + 131072;
      unsigned short* dst = isK ? P.oK : P.oQ;
      const int nloc = isK ? nb - 1024 : nb;
      const int gsel = (nloc >> 6) & 1;
      #pragma unroll
      for (int mi = 0; mi < 8; ++mi)
        #pragma unroll
        for (int r = 0; r < 4; ++r) {
          size_t m = M0 + wm * 128 + mi * 16 + fs * 4 + r;
          int pos = (int)(m & (SEQQ - 1));
          #pragma unroll
          for (int ni = 0; ni < 2; ++ni) {
            int j = gsel * 32 + ni * 16 + fr;
            float cs = tc[pos * 64 + j], sn = ts[pos * 64 + j];
            float ve = acc[mi][ni][r], vo = acc[mi][ni + 2][r];
            dst[m * 1024 + nloc + ni * 16 + fr]       = f2bf(ve * cs - vo * sn);
            dst[m * 1024 + nloc + (ni + 2) * 16 + fr] = f2bf(vo * cs + ve * sn);
          }
        }
    } else {
      const int nloc = nb - ((EPI == EPI_QKG) ? 2048 : 1024);
      #pragma unroll
      for (int mi = 0; mi < 8; ++mi)
        #pragma unroll
        for (int r = 0; r < 4; ++r) {
          size_t m = M0 + wm * 128 + mi * 16 + fs * 4 + r;
          #pragma unroll
          for (int ni = 0; ni < 4; ++ni) {
            float v = acc[mi][ni][r];
            P.oG[m * 2048 + nloc + ni * 16 + fr] = f2bf(v / (1.f + expf(-v)));
          }
        }
    }
  }
}

// ---------------- MFMA retention (round-3 version, 99us known-good) ---------
__global__ __launch_bounds__(256) void retention_mfma(
    const unsigned short* __restrict__ Qx, const unsigned short* __restrict__ Kx,
    const unsigned short* __restrict__ VT, const unsigned short* __restrict__ Gate,
    const float* __restrict__ gnw, const float* __restrict__ gnb,
    unsigned short* __restrict__ Gout) {
  __shared__ __align__(16) unsigned short Ks[32 * 128];
  __shared__ __align__(16) unsigned short Vs[256 * 32];
  __shared__ __align__(16) float Ps[4][16 * 36];
  const int tid = threadIdx.x, w = tid >> 6, lane = tid & 63;
  int bid = blockIdx.x, qt, h, b;
  if (bid < 256) { qt = 31 - (bid >> 3); h = bid & 7; b = 0; }
  else           { int k = bid - 256; qt = k >> 3; h = k & 7; b = 1; }
  const int q0 = qt * 64;
  const int fr = lane & 15, fs = lane >> 4;

  float gamma = 1.f - expf(-3.4657359028f - 0.3960841032f * (float)h);
  float l2g = log2f(gamma);

  size_t qrow = (size_t)b * SEQQ + q0 + w * 16 + fr;
  bf16x8 qf[4];
  #pragma unroll
  for (int ks = 0; ks < 4; ++ks)
    qf[ks] = *(const bf16x8*)(Qx + qrow * 1024 + h * 128 + ks * 32 + fs * 8);

  float fqv[4];
  #pragma unroll
  for (int r = 0; r < 4; ++r)
    fqv[r] = exp2f((float)(q0 + w * 16 + fs * 4 + r) * l2g);

  f32x4 zf = {0.f, 0.f, 0.f, 0.f};
  f32x4 yacc[16];
  #pragma unroll
  for (int i = 0; i < 16; ++i) yacc[i] = zf;

  int cutoff = (int)(27.f / (-l2g));
  int t_start = q0 - cutoff;
  if (t_start < 0) t_start = 0;
  t_start &= ~31;
  size_t kbase = (size_t)b * SEQQ;

  for (int t0 = t_start; t0 < q0 + 64; t0 += 32) {
    __syncthreads();
    #pragma unroll
    for (int c = 0; c < 2; ++c) {
      int ch = w * 2 + c;
      int row = ch * 4 + (lane >> 4);
      int so = (lane & 15) ^ (row & 15);
      gld16(Kx + (kbase + t0 + row) * 1024 + h * 128 + so * 8, Ks + ch * 512);
    }
    #pragma unroll
    for (int c = 0; c < 4; ++c) {
      int ch = w * 4 + c;
      int vrow = ch * 16 + (lane >> 2);
      int so = (lane & 3) ^ ((vrow >> 1) & 3);
      gld16(VT + (size_t)(h * 256 + vrow) * RTOT + kbase + t0 + so * 8, Vs + ch * 512);
    }
    __syncthreads();

    f32x4 sacc[2];
    sacc[0] = zf; sacc[1] = zf;
    #pragma unroll
    for (int nt = 0; nt < 2; ++nt) {
      int row = nt * 16 + fr;
      #pragma unroll
      for (int ks = 0; ks < 4; ++ks) {
        int sl = ks * 4 + fs;
        bf16x8 kf = *(const bf16x8*)(Ks + row * 128 + (sl ^ (row & 15)) * 8);
        sacc[nt] = __builtin_amdgcn_mfma_f32_16x16x32_bf16(qf[ks], kf, sacc[nt], 0, 0, 0);
      }
    }
    float ftv[2];
    ftv[0] = exp2f((float)(t0 + fr)      * -l2g);
    ftv[1] = exp2f((float)(t0 + 16 + fr) * -l2g);
    float* Pw = Ps[w];
    #pragma unroll
    for (int nt = 0; nt < 2; ++nt) {
      #pragma unroll
      for (int r = 0; r < 4; ++r) {
        int sl_ = fs * 4 + r;
        int diff = (q0 + w * 16 + sl_) - (t0 + nt * 16 + fr);
        float v = (diff >= 0) ? sacc[nt][r] * (fqv[r] * ftv[nt]) : 0.f;
        Pw[sl_ * 36 + nt * 16 + fr] = v;
      }
    }
    f32x4 pa = *(const f32x4*)(Pw + fr * 36 + fs * 8);
    f32x4 pb = *(const f32x4*)(Pw + fr * 36 + fs * 8 + 4);
    bf16x8 pf;
    pf[0] = (short)f2bf(pa[0]); pf[1] = (short)f2bf(pa[1]);
    pf[2] = (short)f2bf(pa[2]); pf[3] = (short)f2bf(pa[3]);
    pf[4] = (short)f2bf(pb[0]); pf[5] = (short)f2bf(pb[1]);
    pf[6] = (short)f2bf(pb[2]); pf[7] = (short)f2bf(pb[3]);
    #pragma unroll
    for (int nv = 0; nv < 16; ++nv) {
      int vrow = nv * 16 + fr;
      bf16x8 vf = *(const bf16x8*)(Vs + vrow * 32 + (fs ^ ((vrow >> 1) & 3)) * 8);
      yacc[nv] = __builtin_amdgcn_mfma_f32_16x16x32_bf16(pf, vf, yacc[nv], 0, 0, 0);
    }
  }

  #pragma unroll
  for (int r = 0; r < 4; ++r) {
    float s = 0.f, sq = 0.f;
    #pragma unroll
    for (int nv = 0; nv < 16; ++nv) { float v = yacc[nv][r]; s += v; sq += v * v; }
    #pragma unroll
    for (int msk = 1; msk < 16; msk <<= 1) { s += __shfl_xor(s, msk); sq += __shfl_xor(sq, msk); }
    float mu = s * (1.f / 256.f);
    float var = sq * (1.f / 256.f) - mu * mu;
    float rstd = rsqrtf(var + 1e-5f);
    int srow = q0 + w * 16 + fs * 4 + r;
    size_t mrow = (size_t)b * SEQQ + srow;
    const unsigned short* grow = Gate + mrow * 2048 + h * 256;
    unsigned short* orow = Gout + mrow * 2048 + h * 256;
    #pragma unroll
    for (int nv = 0; nv < 16; ++nv) {
      int col = nv * 16 + fr;
      float yn = (yacc[nv][r] - mu) * rstd * gnw[h * 256 + col] + gnb[h * 256 + col];
      orow[col] = f2bf(bf2f(grow[col]) * yn);
    }
  }
}

// =============================== host ========================================
extern "C" void kernel_launch(void* const* d_in, const int* in_sizes, int n_in,
                              void* d_out, int out_size, void* d_ws, size_t ws_size,
                              hipStream_t stream) {
  const float* X    = (const float*)d_in[0];
  const float* mem  = (const float*)d_in[1];
  const float* ln1w = (const float*)d_in[2];
  const float* ln1b = (const float*)d_in[3];
  const float* ln2w = (const float*)d_in[4];
  const float* ln2b = (const float*)d_in[5];
  const float* Wq   = (const float*)d_in[6];
  const float* Wk   = (const float*)d_in[7];
  const float* Wv   = (const float*)d_in[8];
  const float* Wg   = (const float*)d_in[9];
  const float* Wo   = (const float*)d_in[10];
  const float* gnw  = (const float*)d_in[11];
  const float* gnb  = (const float*)d_in[12];
  const float* cWq  = (const float*)d_in[13];
  const float* cWk  = (const float*)d_in[14];
  const float* cWv  = (const float*)d_in[15];
  const float* cWg  = (const float*)d_in[16];
  const float* cWo  = (const float*)d_in[17];
  const float* cgnw = (const float*)d_in[18];
  const float* cgnb = (const float*)d_in[19];
  const float* W1   = (const float*)d_in[20];
  const float* b1   = (const float*)d_in[21];
  const float* W2   = (const float*)d_in[22];
  const float* b2   = (const float*)d_in[23];
  float* out = (float*)d_out;

  const size_t MB = 1024ull * 1024ull;
  if (ws_size < 106 * MB) return;
  unsigned char* W8 = (unsigned char*)d_ws;
  unsigned short* WqkgT = (unsigned short*)(W8 + 0 * MB);   // 8MB [4096][1024]
  unsigned short* WvT   = (unsigned short*)(W8 + 8 * MB);   // 4MB
  unsigned short* WoT   = (unsigned short*)(W8 + 12 * MB);  // 4MB
  unsigned short* cQGT  = (unsigned short*)(W8 + 16 * MB);  // 6MB [3072][1024]
  unsigned short* cWkT  = (unsigned short*)(W8 + 22 * MB);  // 2MB
  unsigned short* cWvT  = (unsigned short*)(W8 + 24 * MB);  // 4MB
  unsigned short* cWoT  = (unsigned short*)(W8 + 28 * MB);  // 4MB
  float*          tab   = (float*)(W8 + 32 * MB);           // 2MB
  unsigned short* hbuf  = (unsigned short*)(W8 + 34 * MB);  // 8MB
  unsigned short* Qx    = (unsigned short*)(W8 + 42 * MB);  // 8MB (later W1T)
  unsigned short* Kx    = (unsigned short*)(W8 + 50 * MB);  // 8MB (later W2T)
  unsigned short* W1T   = Qx;
  unsigned short* W2T   = Kx;
  unsigned short* VTb   = (unsigned short*)(W8 + 58 * MB);  // 16MB
  unsigned short* Gg    = (unsigned short*)(W8 + 74 * MB);  // 16MB
  unsigned short* Tb    = VTb;                               // FFN mid 32MB
  unsigned short* GoutB = (unsigned short*)(W8 + 90 * MB);  // 16MB
  unsigned short* mem16 = GoutB;                             // 8MB overlay

  // ---- weight prep (Wq/Wk/cWq/cWk column-permuted for pair-in-lane xpos) ----
  transpose_bf16<<<dim3(32, 4, 8),  256, 0, stream>>>(Wq,  WqkgT,               1024, 128, 1);
  transpose_bf16<<<dim3(32, 4, 8),  256, 0, stream>>>(Wk,  WqkgT + 1024 * 1024, 1024, 128, 1);
  transpose_bf16<<<dim3(32, 64, 1), 256, 0, stream>>>(Wg,  WqkgT + 2048 * 1024, 1024, 2048, 0);
  transpose_bf16<<<dim3(32, 8, 8),  256, 0, stream>>>(Wv,  WvT,  1024, 256, 0);
  transpose_bf16<<<dim3(64, 32, 1), 256, 0, stream>>>(Wo,  WoT,  2048, 1024, 0);
  transpose_bf16<<<dim3(32, 4, 8),  256, 0, stream>>>(cWq, cQGT,               1024, 128, 1);
  transpose_bf16<<<dim3(32, 64, 1), 256, 0, stream>>>(cWg, cQGT + 1024 * 1024, 1024, 2048, 0);
  transpose_bf16<<<dim3(32, 4, 8),  256, 0, stream>>>(cWk, cWkT, 1024, 128, 1);
  transpose_bf16<<<dim3(32, 8, 8),  256, 0, stream>>>(cWv, cWvT, 1024, 256, 0);
  transpose_bf16<<<dim3(64, 32, 1), 256, 0, stream>>>(cWo, cWoT, 2048, 1024, 0);
  tabgen<<<512, 256, 0, stream>>>(tab);

  EpiP P{};

  // ---- block 1: self retention ----
  ln_bf16<<<RTOT, 256, 0, stream>>>(X, ln1w, ln1b, hbuf);
  P = EpiP{nullptr, 0, nullptr, nullptr, tab, Qx, Kx, Gg};
  gemm256<EPI_QKG><<<256, 512, 0, stream>>>(hbuf, WqkgT, 16, P);
  P = EpiP{VTb, 4096, nullptr, nullptr, nullptr, nullptr, nullptr, nullptr};
  gemm_mfma<EPI_BF16><<<dim3(32, 16), 256, 0, stream>>>(WvT, 1024, hbuf, 1024, 1024, P);
  retention_mfma<<<dim3(512), 256, 0, stream>>>(Qx, Kx, VTb, Gg, gnw, gnb, GoutB);
  P = EpiP{out, 1024, nullptr, X, nullptr, nullptr, nullptr, nullptr};
  gemm_bn64<EPI_F32_RES><<<dim3(16, 32), 256, 0, stream>>>(GoutB, 2048, WoT, 2048, 2048, P);

  // ---- block 2: cross retention ----
  cvt_bf16<<<2048, 256, 0, stream>>>(mem, mem16, 524288);
  ln_bf16<<<RTOT, 256, 0, stream>>>(out, ln2w, ln2b, hbuf);
  P = EpiP{nullptr, 0, nullptr, nullptr, tab, Qx, nullptr, Gg};
  gemm256<EPI_QG><<<192, 512, 0, stream>>>(hbuf, cQGT, 12, P);
  P = EpiP{Kx, 1024, nullptr, nullptr, tab, nullptr, nullptr, nullptr};
  gemm_bn64<EPI_XPOS><<<dim3(16, 32), 256, 0, stream>>>(mem16, 1024, cWkT, 1024, 1024, P);
  P = EpiP{VTb, 4096, nullptr, nullptr, nullptr, nullptr, nullptr, nullptr};
  gemm_mfma<EPI_BF16><<<dim3(32, 16), 256, 0, stream>>>(cWvT, 1024, mem16, 1024, 1024, P);
  retention_mfma<<<dim3(512), 256, 0, stream>>>(Qx, Kx, VTb, Gg, cgnw, cgnb, GoutB);
  P = EpiP{out, 1024, nullptr, out, nullptr, nullptr, nullptr, nullptr};
  gemm_bn64<EPI_F32_RES><<<dim3(16, 32), 256, 0, stream>>>(GoutB, 2048, cWoT, 2048, 2048, P);

  // ---- FFN ----
  transpose_bf16<<<dim3(32, 128, 1), 256, 0, stream>>>(W1, W1T, 1024, 4096, 0);
  transpose_bf16<<<dim3(128, 32, 1), 256, 0, stream>>>(W2, W2T, 4096, 1024, 0);
  ln_bf16<<<RTOT, 256, 0, stream>>>(out, ln2w, ln2b, hbuf);
  P = EpiP{Tb, 4096, b1, nullptr, nullptr, nullptr, nullptr, nullptr};
  gemm256<EPI_GELU><<<256, 512, 0, stream>>>(hbuf, W1T, 16, P);
  P = EpiP{out, 1024, b2, out, nullptr, nullptr, nullptr, nullptr};
  gemm_bn64<EPI_BRES><<<dim3(16, 32), 256, 0, stream>>>(Tb, 4096, W2T, 4096, 4096, P);
}

// Round 6
// 588.336 us; speedup vs baseline: 1.2384x; 1.1339x over previous
//
#include <hip/hip_runtime.h>
#include <math.h>

// Problem: B=2, S=2048, d=1024, h=8, hd=128, hv=256, vd=2048, f=4096
#define RTOT 4096
#define SEQQ 2048

typedef unsigned int uint32;
typedef __attribute__((ext_vector_type(4))) float f32x4;
typedef __attribute__((ext_vector_type(8))) short bf16x8;

__device__ __forceinline__ unsigned short f2bf(float f) {
  unsigned int u = __float_as_uint(f);
  u = (u + 0x7FFFu + ((u >> 16) & 1u)) >> 16;
  return (unsigned short)u;
}
__device__ __forceinline__ float bf2f(unsigned short h) {
  return __uint_as_float(((unsigned int)h) << 16);
}
__device__ __forceinline__ void gld16(const void* g, void* l) {
  __builtin_amdgcn_global_load_lds(
      (const __attribute__((address_space(1))) uint32*)g,
      (__attribute__((address_space(3))) uint32*)l, 16, 0, 0);
}
__device__ __forceinline__ void bar() {
  asm volatile("" ::: "memory");
  __builtin_amdgcn_s_barrier();
  asm volatile("" ::: "memory");
}
#define VMCNT(n) asm volatile("s_waitcnt vmcnt(" #n ")" ::: "memory")

// ---- tiled transpose f32[R][C] -> bf16[C][R], batched z; optional xpos perm --
__global__ __launch_bounds__(256) void transpose_bf16(
    const float* __restrict__ in, unsigned short* __restrict__ out, int R, int C,
    int perm) {
  __shared__ float t[32][33];
  int z = blockIdx.z;
  in  += (size_t)z * R * C;
  out += (size_t)z * C * R;
  int r0 = blockIdx.x * 32, c0 = blockIdx.y * 32;
  int tx = threadIdx.x & 31, ty = threadIdx.x >> 5;
  #pragma unroll
  for (int i = 0; i < 4; ++i) {
    int r = ty + i * 8;
    t[r][tx] = in[(size_t)(r0 + r) * C + c0 + tx];
  }
  __syncthreads();
  #pragma unroll
  for (int i = 0; i < 4; ++i) {
    int cc = c0 + ty + i * 8;
    if (perm) cc = 64 * (cc >> 6) + ((cc & 1) << 5) + ((cc & 63) >> 1);
    out[(size_t)cc * R + r0 + tx] = f2bf(t[tx][ty + i * 8]);
  }
}

// ---------------- f32 -> bf16 convert ----------------
__global__ __launch_bounds__(256) void cvt_bf16(
    const float* __restrict__ in, unsigned short* __restrict__ out, int n8) {
  int i = blockIdx.x * 256 + threadIdx.x;
  if (i >= n8) return;
  const float4* p = (const float4*)(in + (size_t)i * 8);
  float4 a = p[0], b = p[1];
  bf16x8 v;
  v[0] = (short)f2bf(a.x); v[1] = (short)f2bf(a.y); v[2] = (short)f2bf(a.z); v[3] = (short)f2bf(a.w);
  v[4] = (short)f2bf(b.x); v[5] = (short)f2bf(b.y); v[6] = (short)f2bf(b.z); v[7] = (short)f2bf(b.w);
  *(bf16x8*)(out + (size_t)i * 8) = v;
}

// ---------------- xpos coefficient tables [4][2048*64] f32 -------------------
__global__ __launch_bounds__(256) void tabgen(float* __restrict__ tab) {
  int i = blockIdx.x * 256 + threadIdx.x;   // 131072
  int pos = i >> 6, j = i & 63;
  float bs = (2.f * (float)j + 51.2f) * (1.f / 179.2f);
  float e = (float)pos * (1.f / 512.f);
  float sc = exp2f(e * log2f(bs));
  float invf = exp2f(-(float)j * (13.287712379549449f / 64.f));
  float su, cu;
  sincosf((float)pos * invf, &su, &cu);
  tab[i]            = cu * sc;   // cosQ
  tab[131072 + i]   = su * sc;   // sinQ
  float si = 1.f / sc;
  tab[262144 + i]   = cu * si;   // cosK
  tab[393216 + i]   = su * si;   // sinK
}

// ---------------- LayerNorm -> bf16 ----------------
__global__ __launch_bounds__(256) void ln_bf16(const float* __restrict__ x,
    const float* __restrict__ w, const float* __restrict__ b,
    unsigned short* __restrict__ out) {
  int row = blockIdx.x, tid = threadIdx.x;
  const float* xr = x + (size_t)row * 1024;
  float4 v = *(const float4*)(xr + tid * 4);
  float s  = v.x + v.y + v.z + v.w;
  float ss = v.x*v.x + v.y*v.y + v.z*v.z + v.w*v.w;
  #pragma unroll
  for (int o = 32; o > 0; o >>= 1) { s += __shfl_down(s, o); ss += __shfl_down(ss, o); }
  __shared__ float red[2][4];
  int wid = tid >> 6;
  if ((tid & 63) == 0) { red[0][wid] = s; red[1][wid] = ss; }
  __syncthreads();
  float st  = red[0][0] + red[0][1] + red[0][2] + red[0][3];
  float sst = red[1][0] + red[1][1] + red[1][2] + red[1][3];
  float mu   = st * (1.f / 1024.f);
  float var  = sst * (1.f / 1024.f) - mu * mu;
  float rstd = rsqrtf(var + 1e-5f);
  float4 wv = *(const float4*)(w + tid * 4);
  float4 bv = *(const float4*)(b + tid * 4);
  unsigned short o0 = f2bf((v.x - mu) * rstd * wv.x + bv.x);
  unsigned short o1 = f2bf((v.y - mu) * rstd * wv.y + bv.y);
  unsigned short o2 = f2bf((v.z - mu) * rstd * wv.z + bv.z);
  unsigned short o3 = f2bf((v.w - mu) * rstd * wv.w + bv.w);
  ushort4 o4 = make_ushort4(o0, o1, o2, o3);
  *(ushort4*)(out + (size_t)row * 1024 + tid * 4) = o4;
}

// ---------------- epilogues ----------------
enum { EPI_F32_RES = 0, EPI_BF16 = 1, EPI_XPOS = 2, EPI_GELU = 4, EPI_BRES = 5,
       EPI_QKG = 6, EPI_QG = 7 };

struct EpiP {
  void* C; int ldc;
  const float* bias; const float* resid;
  const float* tab;
  unsigned short* oQ; unsigned short* oK; unsigned short* oG;
};

template<int EPI>
__device__ __forceinline__ void epi_store(size_t m, int n, int N0, float v, const EpiP& P) {
  if constexpr (EPI == EPI_BF16) {
    ((unsigned short*)P.C)[m * P.ldc + n] = f2bf(v);
  } else if constexpr (EPI == EPI_GELU) {
    v += P.bias[n];
    v = 0.5f * v * (1.f + erff(v * 0.70710678f));
    ((unsigned short*)P.C)[m * P.ldc + n] = f2bf(v);
  } else if constexpr (EPI == EPI_BRES) {
    v += P.bias[n] + P.resid[m * P.ldc + n];
    ((float*)P.C)[m * P.ldc + n] = v;
  } else {  // EPI_F32_RES
    v += P.resid[m * P.ldc + n];
    ((float*)P.C)[m * P.ldc + n] = v;
  }
}

// ------- MFMA GEMM 128x128, dbuf + counted vmcnt: C = A * Bt^T --------------
template<int EPI>
__global__ __launch_bounds__(256) void gemm_mfma(
    const unsigned short* __restrict__ A, int lda,
    const unsigned short* __restrict__ Bt, int ldb, int K, EpiP P) {
  __shared__ __align__(16) unsigned short As[2][128 * 32];
  __shared__ __align__(16) unsigned short Bs[2][128 * 32];
  const int tid = threadIdx.x, w = tid >> 6, lane = tid & 63;
  const int M0 = blockIdx.y * 128, N0 = blockIdx.x * 128;
  const int fr = lane & 15, fs = lane >> 4;
  const int srow = lane >> 2, sp = lane & 3;

  f32x4 zf = {0.f, 0.f, 0.f, 0.f};
  f32x4 acc[4][4];
  #pragma unroll
  for (int i = 0; i < 4; ++i)
    #pragma unroll
    for (int j = 0; j < 4; ++j) acc[i][j] = zf;

  auto STAGE = [&](int buf, int k0) {
    #pragma unroll
    for (int c = 0; c < 4; ++c) {
      int ch = w * 4 + c;
      int cc = ch & 7;
      int row = cc * 16 + srow;
      int so = sp ^ ((row >> 1) & 3);
      if (ch < 8) gld16(A  + (size_t)(M0 + row) * lda + k0 + so * 8, &As[buf][cc * 512]);
      else        gld16(Bt + (size_t)(N0 + row) * ldb + k0 + so * 8, &Bs[buf][cc * 512]);
    }
  };

  STAGE(0, 0);
  int cur = 0;
  for (int k0 = 0; k0 < K; k0 += 32) {
    if (k0 + 32 < K) { STAGE(cur ^ 1, k0 + 32); VMCNT(4); }
    else             { VMCNT(0); }
    bar();
    bf16x8 af[4], bfr[4];
    #pragma unroll
    for (int mi = 0; mi < 4; ++mi) {
      int row = (w >> 1) * 64 + mi * 16 + fr;
      af[mi] = *(const bf16x8*)(&As[cur][row * 32 + (fs ^ ((row >> 1) & 3)) * 8]);
    }
    #pragma unroll
    for (int ni = 0; ni < 4; ++ni) {
      int row = (w & 1) * 64 + ni * 16 + fr;
      bfr[ni] = *(const bf16x8*)(&Bs[cur][row * 32 + (fs ^ ((row >> 1) & 3)) * 8]);
    }
    #pragma unroll
    for (int mi = 0; mi < 4; ++mi)
      #pragma unroll
      for (int ni = 0; ni < 4; ++ni)
        acc[mi][ni] = __builtin_amdgcn_mfma_f32_16x16x32_bf16(af[mi], bfr[ni], acc[mi][ni], 0, 0, 0);
    bar();
    cur ^= 1;
  }

  #pragma unroll
  for (int mi = 0; mi < 4; ++mi)
    #pragma unroll
    for (int r = 0; r < 4; ++r) {
      size_t m = M0 + (w >> 1) * 64 + mi * 16 + fs * 4 + r;
      #pragma unroll
      for (int ni = 0; ni < 4; ++ni) {
        int n = N0 + (w & 1) * 64 + ni * 16 + fr;
        epi_store<EPI>(m, n, N0, acc[mi][ni][r], P);
      }
    }
}

// ------- MFMA GEMM 128x64, dbuf + counted vmcnt (N=1024 shapes) -------------
template<int EPI>
__global__ __launch_bounds__(256) void gemm_bn64(
    const unsigned short* __restrict__ A, int lda,
    const unsigned short* __restrict__ Bt, int ldb, int K, EpiP P) {
  __shared__ __align__(16) unsigned short As[2][128 * 32];
  __shared__ __align__(16) unsigned short Bs[2][64 * 32];
  const int tid = threadIdx.x, w = tid >> 6, lane = tid & 63;
  const int M0 = blockIdx.y * 128, N0 = blockIdx.x * 64;
  const int fr = lane & 15, fs = lane >> 4;
  const int srow = lane >> 2, sp = lane & 3;

  f32x4 zf = {0.f, 0.f, 0.f, 0.f};
  f32x4 acc[2][4];
  #pragma unroll
  for (int i = 0; i < 2; ++i)
    #pragma unroll
    for (int j = 0; j < 4; ++j) acc[i][j] = zf;

  auto STAGE = [&](int buf, int k0) {
    #pragma unroll
    for (int c = 0; c < 3; ++c) {
      int ch = w * 3 + c;
      if (ch < 8) {
        int row = ch * 16 + srow;
        int so = sp ^ ((row >> 1) & 3);
        gld16(A + (size_t)(M0 + row) * lda + k0 + so * 8, &As[buf][ch * 512]);
      } else {
        int bch = ch - 8;
        int row = bch * 16 + srow;
        int so = sp ^ ((row >> 1) & 3);
        gld16(Bt + (size_t)(N0 + row) * ldb + k0 + so * 8, &Bs[buf][bch * 512]);
      }
    }
  };

  STAGE(0, 0);
  int cur = 0;
  for (int k0 = 0; k0 < K; k0 += 32) {
    if (k0 + 32 < K) { STAGE(cur ^ 1, k0 + 32); VMCNT(3); }
    else             { VMCNT(0); }
    bar();
    bf16x8 af[2], bfr[4];
    #pragma unroll
    for (int mi = 0; mi < 2; ++mi) {
      int row = w * 32 + mi * 16 + fr;
      af[mi] = *(const bf16x8*)(&As[cur][row * 32 + (fs ^ ((row >> 1) & 3)) * 8]);
    }
    #pragma unroll
    for (int ni = 0; ni < 4; ++ni) {
      int row = ni * 16 + fr;
      bfr[ni] = *(const bf16x8*)(&Bs[cur][row * 32 + (fs ^ ((row >> 1) & 3)) * 8]);
    }
    #pragma unroll
    for (int mi = 0; mi < 2; ++mi)
      #pragma unroll
      for (int ni = 0; ni < 4; ++ni)
        acc[mi][ni] = __builtin_amdgcn_mfma_f32_16x16x32_bf16(af[mi], bfr[ni], acc[mi][ni], 0, 0, 0);
    bar();
    cur ^= 1;
  }

  if constexpr (EPI == EPI_XPOS) {
    int gsel = (N0 >> 6) & 1;
    #pragma unroll
    for (int mi = 0; mi < 2; ++mi)
      #pragma unroll
      for (int r = 0; r < 4; ++r) {
        size_t m = M0 + w * 32 + mi * 16 + fs * 4 + r;
        int pos = (int)(m & (SEQQ - 1));
        #pragma unroll
        for (int ni = 0; ni < 2; ++ni) {
          int j = gsel * 32 + ni * 16 + fr;
          float cs = P.tab[pos * 64 + j], sn = P.tab[131072 + pos * 64 + j];
          float ve = acc[mi][ni][r], vo = acc[mi][ni + 2][r];
          unsigned short* dst = (unsigned short*)P.C;
          dst[m * P.ldc + N0 + ni * 16 + fr]       = f2bf(ve * cs - vo * sn);
          dst[m * P.ldc + N0 + (ni + 2) * 16 + fr] = f2bf(vo * cs + ve * sn);
        }
      }
  } else {
    #pragma unroll
    for (int mi = 0; mi < 2; ++mi)
      #pragma unroll
      for (int r = 0; r < 4; ++r) {
        size_t m = M0 + w * 32 + mi * 16 + fs * 4 + r;
        #pragma unroll
        for (int ni = 0; ni < 4; ++ni) {
          int n = N0 + ni * 16 + fr;
          epi_store<EPI>(m, n, N0, acc[mi][ni][r], P);
        }
      }
  }
}

// ---------------- 256x256 8-wave GEMM, 4-deep counted-vmcnt pipeline --------
template<int EPI>
__global__ __launch_bounds__(512, 2) void gemm256(
    const unsigned short* __restrict__ A,
    const unsigned short* __restrict__ Bt,
    int nbx, EpiP P) {
  __shared__ __align__(16) unsigned short lds[4][2][8192];  // [buf][A|B][256*32]
  const int tid = threadIdx.x, w = tid >> 6, lane = tid & 63;
  int cpx = (int)gridDim.x >> 3;
  int sbid = ((int)blockIdx.x & 7) * cpx + ((int)blockIdx.x >> 3);
  int by = sbid / nbx, bx = sbid - by * nbx;
  const int M0 = by * 256, N0 = bx * 256;
  const int wm = w >> 2, wn = w & 3;
  const int fr = lane & 15, fs = lane >> 4;
  const int srow = lane >> 2;
  const int sslot = (lane & 3) ^ ((lane >> 3) & 3);
  const int rsw = (fr >> 1) & 3;

  f32x4 acc[8][4];
  #pragma unroll
  for (int i = 0; i < 8; ++i)
    #pragma unroll
    for (int j = 0; j < 4; ++j) acc[i][j] = {0.f, 0.f, 0.f, 0.f};

  auto STAGE = [&](int t, int buf) {
    int k0 = t * 32;
    #pragma unroll
    for (int j = 0; j < 4; ++j) {
      int c = w * 4 + j;
      if (c < 16)
        gld16(A  + (size_t)(M0 + c * 16 + srow) * 1024 + k0 + sslot * 8,
              &lds[buf][0][c * 512]);
      else
        gld16(Bt + (size_t)(N0 + (c - 16) * 16 + srow) * 1024 + k0 + sslot * 8,
              &lds[buf][1][(c - 16) * 512]);
    }
  };
  auto COMPUTE = [&](int t) {
    const unsigned short* la = &lds[t & 3][0][wm * 128 * 32];
    const unsigned short* lb = &lds[t & 3][1][wn * 64 * 32];
    bf16x8 a[8], b[4];
    #pragma unroll
    for (int ni = 0; ni < 4; ++ni)
      b[ni] = *(const bf16x8*)(lb + (ni * 16 + fr) * 32 + ((fs ^ rsw) * 8));
    #pragma unroll
    for (int mi = 0; mi < 8; ++mi)
      a[mi] = *(const bf16x8*)(la + (mi * 16 + fr) * 32 + ((fs ^ rsw) * 8));
    #pragma unroll
    for (int mi = 0; mi < 8; ++mi)
      #pragma unroll
      for (int ni = 0; ni < 4; ++ni)
        acc[mi][ni] = __builtin_amdgcn_mfma_f32_16x16x32_bf16(a[mi], b[ni], acc[mi][ni], 0, 0, 0);
  };

  STAGE(0, 0); STAGE(1, 1); STAGE(2, 2);
  for (int t = 0; t < 29; ++t) {
    STAGE(t + 3, (t + 3) & 3);
    VMCNT(12);
    bar();
    COMPUTE(t);
    bar();
  }
  VMCNT(8);  bar(); COMPUTE(29); bar();
  VMCNT(4);  bar(); COMPUTE(30); bar();
  VMCNT(0);  bar(); COMPUTE(31);

  if constexpr (EPI == EPI_GELU) {
    #pragma unroll
    for (int mi = 0; mi < 8; ++mi)
      #pragma unroll
      for (int r = 0; r < 4; ++r) {
        size_t m = M0 + wm * 128 + mi * 16 + fs * 4 + r;
        #pragma unroll
        for (int ni = 0; ni < 4; ++ni) {
          int n = N0 + wn * 64 + ni * 16 + fr;
          float v = acc[mi][ni][r] + P.bias[n];
          v = 0.5f * v * (1.f + erff(v * 0.70710678f));
          ((unsigned short*)P.C)[m * P.ldc + n] = f2bf(v);
        }
      }
  } else {  // EPI_QKG / EPI_QG
    const int nb = N0 + wn * 64;
    const bool isQ = nb < 1024;
    const bool isK = (EPI == EPI_QKG) && !isQ && (nb < 2048);
    if (isQ || isK) {
      const float* tc = isK ? P.tab + 262144 : P.tab;
      const float* ts = tc + 131072;
      unsigned short* dst = isK ? P.oK : P.oQ;
      const int nloc = isK ? nb - 1024 : nb;
      const int gsel = (nloc >> 6) & 1;
      #pragma unroll
      for (int mi = 0; mi < 8; ++mi)
        #pragma unroll
        for (int r = 0; r < 4; ++r) {
          size_t m = M0 + wm * 128 + mi * 16 + fs * 4 + r;
          int pos = (int)(m & (SEQQ - 1));
          #pragma unroll
          for (int ni = 0; ni < 2; ++ni) {
            int j = gsel * 32 + ni * 16 + fr;
            float cs = tc[pos * 64 + j], sn = ts[pos * 64 + j];
            float ve = acc[mi][ni][r], vo = acc[mi][ni + 2][r];
            dst[m * 1024 + nloc + ni * 16 + fr]       = f2bf(ve * cs - vo * sn);
            dst[m * 1024 + nloc + (ni + 2) * 16 + fr] = f2bf(vo * cs + ve * sn);
          }
        }
    } else {
      const int nloc = nb - ((EPI == EPI_QKG) ? 2048 : 1024);
      #pragma unroll
      for (int mi = 0; mi < 8; ++mi)
        #pragma unroll
        for (int r = 0; r < 4; ++r) {
          size_t m = M0 + wm * 128 + mi * 16 + fs * 4 + r;
          #pragma unroll
          for (int ni = 0; ni < 4; ++ni) {
            float v = acc[mi][ni][r];
            P.oG[m * 2048 + nloc + ni * 16 + fr] = f2bf(v / (1.f + expf(-v)));
          }
        }
    }
  }
}

// -------- MFMA retention: r3 compute structure + dbuf + counted vmcnt -------
__global__ __launch_bounds__(256) void retention_mfma(
    const unsigned short* __restrict__ Qx, const unsigned short* __restrict__ Kx,
    const unsigned short* __restrict__ VT, const unsigned short* __restrict__ Gate,
    const float* __restrict__ gnw, const float* __restrict__ gnb,
    unsigned short* __restrict__ Gout) {
  __shared__ __align__(16) unsigned short Ks[2][32 * 128];
  __shared__ __align__(16) unsigned short Vs[2][256 * 32];
  __shared__ __align__(16) float Ps[4][16 * 36];
  const int tid = threadIdx.x, w = tid >> 6, lane = tid & 63;
  int bid = blockIdx.x, qt, h, b;
  if (bid < 256) { qt = 31 - (bid >> 3); h = bid & 7; b = 0; }
  else           { int k = bid - 256; qt = k >> 3; h = k & 7; b = 1; }
  const int q0 = qt * 64;
  const int fr = lane & 15, fs = lane >> 4;

  float gamma = 1.f - expf(-3.4657359028f - 0.3960841032f * (float)h);
  float l2g = log2f(gamma);

  size_t qrow = (size_t)b * SEQQ + q0 + w * 16 + fr;
  bf16x8 qf[4];
  #pragma unroll
  for (int ks = 0; ks < 4; ++ks)
    qf[ks] = *(const bf16x8*)(Qx + qrow * 1024 + h * 128 + ks * 32 + fs * 8);

  float fqv[4];
  #pragma unroll
  for (int r = 0; r < 4; ++r)
    fqv[r] = exp2f((float)(q0 + w * 16 + fs * 4 + r) * l2g);

  f32x4 zf = {0.f, 0.f, 0.f, 0.f};
  f32x4 yacc[16];
  #pragma unroll
  for (int i = 0; i < 16; ++i) yacc[i] = zf;

  int cutoff = (int)(27.f / (-l2g));
  int t_start = q0 - cutoff;
  if (t_start < 0) t_start = 0;
  t_start &= ~31;
  size_t kbase = (size_t)b * SEQQ;

  auto STAGE = [&](int buf, int t0) {
    #pragma unroll
    for (int c = 0; c < 2; ++c) {
      int ch = w * 2 + c;
      int row = ch * 4 + (lane >> 4);
      int so = (lane & 15) ^ (row & 15);
      gld16(Kx + (kbase + t0 + row) * 1024 + h * 128 + so * 8, &Ks[buf][ch * 512]);
    }
    #pragma unroll
    for (int c = 0; c < 4; ++c) {
      int ch = w * 4 + c;
      int vrow = ch * 16 + (lane >> 2);
      int so = (lane & 3) ^ ((vrow >> 1) & 3);
      gld16(VT + (size_t)(h * 256 + vrow) * RTOT + kbase + t0 + so * 8, &Vs[buf][ch * 512]);
    }
  };

  STAGE(0, t_start);
  int cur = 0;
  for (int t0 = t_start; t0 < q0 + 64; t0 += 32) {
    if (t0 + 32 < q0 + 64) { STAGE(cur ^ 1, t0 + 32); VMCNT(6); }
    else                   { VMCNT(0); }
    bar();

    f32x4 sacc[2];
    sacc[0] = zf; sacc[1] = zf;
    #pragma unroll
    for (int nt = 0; nt < 2; ++nt) {
      int row = nt * 16 + fr;
      #pragma unroll
      for (int ks = 0; ks < 4; ++ks) {
        int sl = ks * 4 + fs;
        bf16x8 kf = *(const bf16x8*)(&Ks[cur][row * 128 + (sl ^ (row & 15)) * 8]);
        sacc[nt] = __builtin_amdgcn_mfma_f32_16x16x32_bf16(qf[ks], kf, sacc[nt], 0, 0, 0);
      }
    }
    float ftv[2];
    ftv[0] = exp2f((float)(t0 + fr)      * -l2g);
    ftv[1] = exp2f((float)(t0 + 16 + fr) * -l2g);
    float* Pw = Ps[w];
    #pragma unroll
    for (int nt = 0; nt < 2; ++nt) {
      #pragma unroll
      for (int r = 0; r < 4; ++r) {
        int sl_ = fs * 4 + r;
        int diff = (q0 + w * 16 + sl_) - (t0 + nt * 16 + fr);
        float v = (diff >= 0) ? sacc[nt][r] * (fqv[r] * ftv[nt]) : 0.f;
        Pw[sl_ * 36 + nt * 16 + fr] = v;
      }
    }
    f32x4 pa = *(const f32x4*)(Pw + fr * 36 + fs * 8);
    f32x4 pb = *(const f32x4*)(Pw + fr * 36 + fs * 8 + 4);
    bf16x8 pf;
    pf[0] = (short)f2bf(pa[0]); pf[1] = (short)f2bf(pa[1]);
    pf[2] = (short)f2bf(pa[2]); pf[3] = (short)f2bf(pa[3]);
    pf[4] = (short)f2bf(pb[0]); pf[5] = (short)f2bf(pb[1]);
    pf[6] = (short)f2bf(pb[2]); pf[7] = (short)f2bf(pb[3]);
    #pragma unroll
    for (int nv = 0; nv < 16; ++nv) {
      int vrow = nv * 16 + fr;
      bf16x8 vf = *(const bf16x8*)(&Vs[cur][vrow * 32 + (fs ^ ((vrow >> 1) & 3)) * 8]);
      yacc[nv] = __builtin_amdgcn_mfma_f32_16x16x32_bf16(pf, vf, yacc[nv], 0, 0, 0);
    }
    bar();
    cur ^= 1;
  }

  #pragma unroll
  for (int r = 0; r < 4; ++r) {
    float s = 0.f, sq = 0.f;
    #pragma unroll
    for (int nv = 0; nv < 16; ++nv) { float v = yacc[nv][r]; s += v; sq += v * v; }
    #pragma unroll
    for (int msk = 1; msk < 16; msk <<= 1) { s += __shfl_xor(s, msk); sq += __shfl_xor(sq, msk); }
    float mu = s * (1.f / 256.f);
    float var = sq * (1.f / 256.f) - mu * mu;
    float rstd = rsqrtf(var + 1e-5f);
    int srow = q0 + w * 16 + fs * 4 + r;
    size_t mrow = (size_t)b * SEQQ + srow;
    const unsigned short* grow = Gate + mrow * 2048 + h * 256;
    unsigned short* orow = Gout + mrow * 2048 + h * 256;
    #pragma unroll
    for (int nv = 0; nv < 16; ++nv) {
      int col = nv * 16 + fr;
      float yn = (yacc[nv][r] - mu) * rstd * gnw[h * 256 + col] + gnb[h * 256 + col];
      orow[col] = f2bf(bf2f(grow[col]) * yn);
    }
  }
}

// =============================== host ========================================
extern "C" void kernel_launch(void* const* d_in, const int* in_sizes, int n_in,
                              void* d_out, int out_size, void* d_ws, size_t ws_size,
                              hipStream_t stream) {
  const float* X    = (const float*)d_in[0];
  const float* mem  = (const float*)d_in[1];
  const float* ln1w = (const float*)d_in[2];
  const float* ln1b = (const float*)d_in[3];
  const float* ln2w = (const float*)d_in[4];
  const float* ln2b = (const float*)d_in[5];
  const float* Wq   = (const float*)d_in[6];
  const float* Wk   = (const float*)d_in[7];
  const float* Wv   = (const float*)d_in[8];
  const float* Wg   = (const float*)d_in[9];
  const float* Wo   = (const float*)d_in[10];
  const float* gnw  = (const float*)d_in[11];
  const float* gnb  = (const float*)d_in[12];
  const float* cWq  = (const float*)d_in[13];
  const float* cWk  = (const float*)d_in[14];
  const float* cWv  = (const float*)d_in[15];
  const float* cWg  = (const float*)d_in[16];
  const float* cWo  = (const float*)d_in[17];
  const float* cgnw = (const float*)d_in[18];
  const float* cgnb = (const float*)d_in[19];
  const float* W1   = (const float*)d_in[20];
  const float* b1   = (const float*)d_in[21];
  const float* W2   = (const float*)d_in[22];
  const float* b2   = (const float*)d_in[23];
  float* out = (float*)d_out;

  const size_t MB = 1024ull * 1024ull;
  if (ws_size < 106 * MB) return;
  unsigned char* W8 = (unsigned char*)d_ws;
  unsigned short* WqkgT = (unsigned short*)(W8 + 0 * MB);   // 8MB [4096][1024]
  unsigned short* WvT   = (unsigned short*)(W8 + 8 * MB);   // 4MB
  unsigned short* WoT   = (unsigned short*)(W8 + 12 * MB);  // 4MB
  unsigned short* cQGT  = (unsigned short*)(W8 + 16 * MB);  // 6MB [3072][1024]
  unsigned short* cWkT  = (unsigned short*)(W8 + 22 * MB);  // 2MB
  unsigned short* cWvT  = (unsigned short*)(W8 + 24 * MB);  // 4MB
  unsigned short* cWoT  = (unsigned short*)(W8 + 28 * MB);  // 4MB
  float*          tab   = (float*)(W8 + 32 * MB);           // 2MB
  unsigned short* hbuf  = (unsigned short*)(W8 + 34 * MB);  // 8MB
  unsigned short* Qx    = (unsigned short*)(W8 + 42 * MB);  // 8MB (later W1T)
  unsigned short* Kx    = (unsigned short*)(W8 + 50 * MB);  // 8MB (later W2T)
  unsigned short* W1T   = Qx;
  unsigned short* W2T   = Kx;
  unsigned short* VTb   = (unsigned short*)(W8 + 58 * MB);  // 16MB
  unsigned short* Gg    = (unsigned short*)(W8 + 74 * MB);  // 16MB
  unsigned short* Tb    = VTb;                               // FFN mid 32MB
  unsigned short* GoutB = (unsigned short*)(W8 + 90 * MB);  // 16MB
  unsigned short* mem16 = GoutB;                             // 8MB overlay

  // ---- weight prep (Wq/Wk/cWq/cWk column-permuted for pair-in-lane xpos) ----
  transpose_bf16<<<dim3(32, 4, 8),  256, 0, stream>>>(Wq,  WqkgT,               1024, 128, 1);
  transpose_bf16<<<dim3(32, 4, 8),  256, 0, stream>>>(Wk,  WqkgT + 1024 * 1024, 1024, 128, 1);
  transpose_bf16<<<dim3(32, 64, 1), 256, 0, stream>>>(Wg,  WqkgT + 2048 * 1024, 1024, 2048, 0);
  transpose_bf16<<<dim3(32, 8, 8),  256, 0, stream>>>(Wv,  WvT,  1024, 256, 0);
  transpose_bf16<<<dim3(64, 32, 1), 256, 0, stream>>>(Wo,  WoT,  2048, 1024, 0);
  transpose_bf16<<<dim3(32, 4, 8),  256, 0, stream>>>(cWq, cQGT,               1024, 128, 1);
  transpose_bf16<<<dim3(32, 64, 1), 256, 0, stream>>>(cWg, cQGT + 1024 * 1024, 1024, 2048, 0);
  transpose_bf16<<<dim3(32, 4, 8),  256, 0, stream>>>(cWk, cWkT, 1024, 128, 1);
  transpose_bf16<<<dim3(32, 8, 8),  256, 0, stream>>>(cWv, cWvT, 1024, 256, 0);
  transpose_bf16<<<dim3(64, 32, 1), 256, 0, stream>>>(cWo, cWoT, 2048, 1024, 0);
  tabgen<<<512, 256, 0, stream>>>(tab);

  EpiP P{};

  // ---- block 1: self retention ----
  ln_bf16<<<RTOT, 256, 0, stream>>>(X, ln1w, ln1b, hbuf);
  P = EpiP{nullptr, 0, nullptr, nullptr, tab, Qx, Kx, Gg};
  gemm256<EPI_QKG><<<256, 512, 0, stream>>>(hbuf, WqkgT, 16, P);
  P = EpiP{VTb, 4096, nullptr, nullptr, nullptr, nullptr, nullptr, nullptr};
  gemm_mfma<EPI_BF16><<<dim3(32, 16), 256, 0, stream>>>(WvT, 1024, hbuf, 1024, 1024, P);
  retention_mfma<<<dim3(512), 256, 0, stream>>>(Qx, Kx, VTb, Gg, gnw, gnb, GoutB);
  P = EpiP{out, 1024, nullptr, X, nullptr, nullptr, nullptr, nullptr};
  gemm_bn64<EPI_F32_RES><<<dim3(16, 32), 256, 0, stream>>>(GoutB, 2048, WoT, 2048, 2048, P);

  // ---- block 2: cross retention ----
  cvt_bf16<<<2048, 256, 0, stream>>>(mem, mem16, 524288);
  ln_bf16<<<RTOT, 256, 0, stream>>>(out, ln2w, ln2b, hbuf);
  P = EpiP{nullptr, 0, nullptr, nullptr, tab, Qx, nullptr, Gg};
  gemm256<EPI_QG><<<192, 512, 0, stream>>>(hbuf, cQGT, 12, P);
  P = EpiP{Kx, 1024, nullptr, nullptr, tab + 262144, nullptr, nullptr, nullptr};
  gemm_bn64<EPI_XPOS><<<dim3(16, 32), 256, 0, stream>>>(mem16, 1024, cWkT, 1024, 1024, P);
  P = EpiP{VTb, 4096, nullptr, nullptr, nullptr, nullptr, nullptr, nullptr};
  gemm_mfma<EPI_BF16><<<dim3(32, 16), 256, 0, stream>>>(cWvT, 1024, mem16, 1024, 1024, P);
  retention_mfma<<<dim3(512), 256, 0, stream>>>(Qx, Kx, VTb, Gg, cgnw, cgnb, GoutB);
  P = EpiP{out, 1024, nullptr, out, nullptr, nullptr, nullptr, nullptr};
  gemm_bn64<EPI_F32_RES><<<dim3(16, 32), 256, 0, stream>>>(GoutB, 2048, cWoT, 2048, 2048, P);

  // ---- FFN ----
  transpose_bf16<<<dim3(32, 128, 1), 256, 0, stream>>>(W1, W1T, 1024, 4096, 0);
  transpose_bf16<<<dim3(128, 32, 1), 256, 0, stream>>>(W2, W2T, 4096, 1024, 0);
  ln_bf16<<<RTOT, 256, 0, stream>>>(out, ln2w, ln2b, hbuf);
  P = EpiP{Tb, 4096, b1, nullptr, nullptr, nullptr, nullptr, nullptr};
  gemm256<EPI_GELU><<<256, 512, 0, stream>>>(hbuf, W1T, 16, P);
  P = EpiP{out, 1024, b2, out, nullptr, nullptr, nullptr, nullptr};
  gemm_bn64<EPI_BRES><<<dim3(16, 32), 256, 0, stream>>>(Tb, 4096, W2T, 4096, 4096, P);
}